// Round 9
// baseline (5936.001 us; speedup 1.0000x reference)
//
#include <hip/hip_runtime.h>
#include <math.h>

#define B_  256
#define T_  1024
#define S_  8
#define H_  256
#define L_  32
#define RH_ 32
#define NC  16   // clusters (batch groups of 16)
#define CB  16   // blocks per cluster (16 H-rows each)
#define MB  16   // batch rows per cluster
#define NR  16   // H rows per block
#define TPB 256  // 4 waves: w0=layer0, w1=layer1 x-side, w2=layer1 h-side, w3=LN/dt
#define FH  (B_*H_)   // 65536 floats per parity plane
#define CS  (MB*H_)   // 4096 floats: one cluster's slice of a plane

typedef __attribute__((ext_vector_type(8))) short bf16x8;   // 8 bf16 = 4 VGPRs
typedef __attribute__((ext_vector_type(4))) float f32x4;
typedef unsigned long long ull;

__device__ __forceinline__ void split_bf16(float v, short& hi, short& lo) {
    unsigned ub = __float_as_uint(v);
    float hf = __uint_as_float(ub & 0xffff0000u);   // truncate to bf16 (exact residual below)
    hi = (short)(ub >> 16);
    lo = (short)(__float_as_uint(v - hf) >> 16);    // residual truncated to bf16: ~2^-16 rel total
}

__device__ __forceinline__ void vwait0() { asm volatile("s_waitcnt vmcnt(0)" ::: "memory"); }

// Global counter poll: all 64 lanes load the SAME address -> one coalesced
// request per iteration per wave (r0's poll-traffic class).
__device__ __forceinline__ void gpoll(const int* p, int tgt) {
    while (__hip_atomic_load(p, __ATOMIC_RELAXED, __HIP_MEMORY_SCOPE_AGENT) < tgt) {}
}
__device__ __forceinline__ void gadd(int* p) {
    __hip_atomic_fetch_add(p, 1, __ATOMIC_RELAXED, __HIP_MEMORY_SCOPE_AGENT);
}
// Intra-block LDS flags (release/acquire, workgroup scope). The release store
// waits the WAVE's outstanding ds ops (lgkmcnt) -> covers all lanes' writes.
__device__ __forceinline__ void lwait(const int* f, int tgt) {
    while (__hip_atomic_load((int*)f, __ATOMIC_ACQUIRE, __HIP_MEMORY_SCOPE_WORKGROUP) < tgt) {}
}
__device__ __forceinline__ void lset(int* f, int v) {
    __hip_atomic_store(f, v, __ATOMIC_RELEASE, __HIP_MEMORY_SCOPE_WORKGROUP);
}

// Fragment-order exchange (r8-proven): per kb, wave reads base + lane*32B,
// fully contiguous 2KB. Load and unpack identical to r8 -> bit-identical.
__device__ __forceinline__ void exch_load(const float* src, int lane, ull (&araw)[32]) {
    const ull* hsrc = (const ull*)src;
    #pragma unroll
    for (int u = 0; u < 32; ++u) {
        int kb = u >> 2, uu = u & 3;
        araw[u] = __hip_atomic_load(&hsrc[kb*256 + lane*4 + uu],
                                    __ATOMIC_RELAXED, __HIP_MEMORY_SCOPE_AGENT);
    }
}
__device__ __forceinline__ void frag_mfma(
    const ull (&araw)[32],
    const bf16x8 (&whi)[2][8], const bf16x8 (&wlo)[2][8],
    f32x4& accg, f32x4& accf)
{
    #pragma unroll
    for (int kb = 0; kb < 8; ++kb) {
        bf16x8 ahi, alo;
        #pragma unroll
        for (int uu = 0; uu < 4; ++uu) {
            ull d = araw[kb*4 + uu];
            float f0 = __uint_as_float((unsigned)d);
            float f1 = __uint_as_float((unsigned)(d >> 32));
            short h_, l_;
            split_bf16(f0, h_, l_); ahi[uu*2]   = h_; alo[uu*2]   = l_;
            split_bf16(f1, h_, l_); ahi[uu*2+1] = h_; alo[uu*2+1] = l_;
        }
        accg = __builtin_amdgcn_mfma_f32_16x16x32_bf16(ahi, whi[0][kb], accg, 0,0,0);
        accg = __builtin_amdgcn_mfma_f32_16x16x32_bf16(alo, whi[0][kb], accg, 0,0,0);
        accg = __builtin_amdgcn_mfma_f32_16x16x32_bf16(ahi, wlo[0][kb], accg, 0,0,0);
        accf = __builtin_amdgcn_mfma_f32_16x16x32_bf16(ahi, whi[1][kb], accf, 0,0,0);
        accf = __builtin_amdgcn_mfma_f32_16x16x32_bf16(alo, whi[1][kb], accf, 0,0,0);
        accf = __builtin_amdgcn_mfma_f32_16x16x32_bf16(ahi, wlo[1][kb], accf, 0,0,0);
    }
}

__global__ void __launch_bounds__(TPB, 1)
liquid_cfc_mfma(const float* __restrict__ xs,      // [B,T,S]
                const float* __restrict__ tstamp,  // [B,T]
                const float* __restrict__ ln_g, const float* __restrict__ ln_b,
                const float* __restrict__ bb_w0, const float* __restrict__ bb_b0,
                const float* __restrict__ gx_w0, const float* __restrict__ gx_b0,
                const float* __restrict__ gh_w0, const float* __restrict__ gb0,
                const float* __restrict__ lt0,
                const float* __restrict__ bb_w1, const float* __restrict__ bb_b1,
                const float* __restrict__ gx_w1, const float* __restrict__ gx_b1,
                const float* __restrict__ gh_w1, const float* __restrict__ gb1,
                const float* __restrict__ lt1,
                const float* __restrict__ lp_w, const float* __restrict__ lp_b,
                const float* __restrict__ r1_w, const float* __restrict__ r1_b,
                const float* __restrict__ r2_w, const float* __restrict__ r2_b,
                float* __restrict__ out,
                int*   bar,     // [NC*64] per cluster: cntA @+0, cntB @+16, cntC @+32
                float* h0pub,   // [2][NC][CS] fp32, fragment-order exchange (r8)
                float* h1pub,   // [2][NC][CS]
                float* h1fin,   // [B][H] fp32 final h1, row-major (latent tail)
                float* latg)    // [B][L]
{
    const int tid  = threadIdx.x, lane = tid & 63, wid = tid >> 6;
    const int blk  = blockIdx.x,  c = blk >> 4,    j  = blk & 15;
    const int b0   = c * MB,      r0 = j * NR;
    const int n    = lane & 15,   quad = lane >> 4;
    int* cntA = &bar[c*64];
    int* cntB = &bar[c*64 + 16];
    int* cntC = &bar[c*64 + 32];

    // Producer-side fragment-layout constants for k = r0 + n (r8-identical)
    const int kbp = j >> 1;
    const int qkp = ((j & 1) << 1) | (n >> 3);
    const int pbase = ((kbp*4 + qkp)*16)*8 + (n & 7);

    // Parity-depth LDS buffers (depths proven r4/r5) + dependency flags.
    // flag semantics: sflag[X] = t+1  <=>  wave X completed its epoch-t role.
    //  w3 writes xn[t&1],dt[t&3] then sets f3=t+1 (needs f0>=t-1, f2>=t-2: reuse)
    //  w0 epoch t: gpoll cntA>=32t-16; loads; mfma; lwait f3>=t+1; epilogue;
    //     drain; cntA+=1; f0=t+1
    //  w1 epoch t: gpoll cntA>=32t-16; loads; drain; cntA+=1 (read-ack, early);
    //     mfma; lwait f2>=t-1 (pg reuse); write pg[t&1]; f1=t+1
    //  w2 epoch t: gpoll cntB>=16(t-1); loads; mfma; lwait f1>=t+1, f3>=t;
    //     epilogue (dt[(t-1)&3], pg[t&1]); drain; cntB+=1; f2=t+1
    // Safety of summed cntA (first-violation induction): a wave cannot pass
    // 32t-16 unless ALL wave0 pubs(t-1) AND ALL wave1 read-acks(t-1) happened.
    __shared__ float s_xn[2][16][9];
    __shared__ float s_dt[4][16];
    __shared__ float s_gx0[16][9], s_bb0x[16][9];
    __shared__ float s_bg0[16], s_bf0[16], s_sp0[16];
    __shared__ float s_bg1[16], s_bf1[16], s_sp1[16];
    __shared__ float s_pg[2][16][17], s_pf[2][16][17];
    __shared__ int   sflag[4];

    // ---- one-time LDS init ----
    if (tid < 4) sflag[tid] = 0;
    if (tid < 16) {
        s_bg0[tid] = gx_b0[r0+tid] + gb0[r0+tid];
        s_bf0[tid] = bb_b0[r0+tid];
        s_sp0[tid] = log1pf(expf(lt0[r0+tid]));
        s_bg1[tid] = gx_b1[r0+tid] + gb1[r0+tid];
        s_bf1[tid] = bb_b1[r0+tid];
        s_sp1[tid] = log1pf(expf(lt1[r0+tid]));
    }
    if (tid < 128) {
        int r = tid >> 3, s = tid & 7;
        s_gx0[r][s]  = gx_w0[(r0+r)*S_ + s];
        s_bb0x[r][s] = bb_w0[(r0+r)*(S_+H_) + s];
    }

    // ---- one-time: weight slices -> bf16 hi/lo MFMA B-fragments (r8-identical) ----
    bf16x8 whi[2][8], wlo[2][8];
    if (wid < 3) {
        const float* base[2]; int st[2], of[2];
        if (wid == 0) { base[0]=gh_w0; st[0]=H_;   of[0]=0;  base[1]=bb_w0; st[1]=S_+H_; of[1]=S_; }
        else if (wid == 1) { base[0]=gx_w1; st[0]=H_; of[0]=0; base[1]=bb_w1; st[1]=2*H_; of[1]=0; }
        else { base[0]=gh_w1; st[0]=H_; of[0]=0; base[1]=bb_w1; st[1]=2*H_; of[1]=H_; }
        int row = r0 + n;
        for (int mt = 0; mt < 2; ++mt) {
            const float* bp = base[mt] + (size_t)row * st[mt] + of[mt];
            for (int kb = 0; kb < 8; ++kb) {
                const float* sp = bp + kb*32 + quad*8;
                #pragma unroll
                for (int jj = 0; jj < 8; ++jj) {
                    short h_, l_;
                    split_bf16(sp[jj], h_, l_);
                    whi[mt][kb][jj] = h_; wlo[mt][kb][jj] = l_;
                }
            }
        }
    }
    float lngv[8], lnbv[8];
    if (wid == 3 && lane < 16) {
        #pragma unroll
        for (int s = 0; s < 8; ++s) { lngv[s] = ln_g[s]; lnbv[s] = ln_b[s]; }
    }
    float h0own[4] = {0.f,0.f,0.f,0.f};
    float h1own[4] = {0.f,0.f,0.f,0.f};
    float tsPrev = 0.f;
    __syncthreads();   // the ONLY block-wide barrier (init)

    // ---- main loop: dependency-driven, no __syncthreads ----
    for (int t = 0; t <= T_; ++t) {
        const int p = t & 1, q = 1 - p;

        if (wid == 0) {
            if (t < T_) {
                if (t >= 1) gpoll(cntA, 32*t - 16);
                ull araw[32];
                exch_load(h0pub + (size_t)q*FH + (size_t)c*CS, lane, araw);
                f32x4 accg = {0.f,0.f,0.f,0.f}, accf = {0.f,0.f,0.f,0.f};
                frag_mfma(araw, whi, wlo, accg, accf);
                lwait(&sflag[3], t + 1);   // xn[p], dt[t&3] ready
                #pragma unroll
                for (int i = 0; i < 4; ++i) {
                    int m = quad*4 + i;
                    float aG = accg[i] + s_bg0[n];
                    float aF = accf[i] + s_bf0[n];
                    #pragma unroll
                    for (int s = 0; s < 8; ++s) {
                        float xv = s_xn[p][m][s];
                        aG += s_gx0[n][s] * xv;
                        aF += s_bb0x[n][s] * xv;
                    }
                    float g   = 1.f / (1.f + expf(-aG));
                    float f   = tanhf(aF);
                    float dec = expf(-s_dt[t & 3][m] * (s_sp0[n] + fabsf(g)));
                    h0own[i]  = dec * h0own[i] + (1.f - dec) * f;
                    __hip_atomic_store(&h0pub[(size_t)p*FH + (size_t)c*CS + pbase + m*8],
                                       h0own[i], __ATOMIC_RELAXED, __HIP_MEMORY_SCOPE_AGENT);
                }
                vwait0();                      // pubs drained
                if (lane == 0) gadd(cntA);     // pub-ack (subsumes own read-ack)
                if (lane == 0) lset(&sflag[0], t + 1);
            }
        } else if (wid == 1) {
            if (t >= 1) {
                gpoll(cntA, 32*t - 16);
                ull araw[32];
                exch_load(h0pub + (size_t)q*FH + (size_t)c*CS, lane, araw);
                vwait0();                      // data captured in registers
                if (lane == 0) gadd(cntA);     // EARLY read-ack: releases WAR
                f32x4 accg = {0.f,0.f,0.f,0.f}, accf = {0.f,0.f,0.f,0.f};
                frag_mfma(araw, whi, wlo, accg, accf);
                lwait(&sflag[2], t - 1);       // pg[p] slot consumed (w2 @ t-2)
                #pragma unroll
                for (int i = 0; i < 4; ++i) {
                    s_pg[p][quad*4+i][n] = accg[i];
                    s_pf[p][quad*4+i][n] = accf[i];
                }
                if (lane == 0) lset(&sflag[1], t + 1);
            }
        } else if (wid == 2) {
            if (t >= 1) {
                gpoll(cntB, 16*(t - 1));
                ull araw[32];
                exch_load(h1pub + (size_t)q*FH + (size_t)c*CS, lane, araw);
                f32x4 accg = {0.f,0.f,0.f,0.f}, accf = {0.f,0.f,0.f,0.f};
                frag_mfma(araw, whi, wlo, accg, accf);
                lwait(&sflag[1], t + 1);       // pg/pf of this epoch
                lwait(&sflag[3], t);           // dt[(t-1)&3] written at t-1
                #pragma unroll
                for (int i = 0; i < 4; ++i) {
                    int m = quad*4 + i;
                    float aG = accg[i] + s_pg[p][m][n] + s_bg1[n];
                    float aF = accf[i] + s_pf[p][m][n] + s_bf1[n];
                    float g   = 1.f / (1.f + expf(-aG));
                    float f   = tanhf(aF);
                    float dec = expf(-s_dt[(t-1) & 3][m] * (s_sp1[n] + fabsf(g)));
                    h1own[i]  = dec * h1own[i] + (1.f - dec) * f;
                    __hip_atomic_store(&h1pub[(size_t)p*FH + (size_t)c*CS + pbase + m*8],
                                       h1own[i], __ATOMIC_RELAXED, __HIP_MEMORY_SCOPE_AGENT);
                    if (t == T_)   // bit-exact fp32 row-major copy for the tail
                        __hip_atomic_store(&h1fin[(size_t)(b0+m)*H_ + (r0+n)], h1own[i],
                                           __ATOMIC_RELAXED, __HIP_MEMORY_SCOPE_AGENT);
                }
                vwait0();
                if (lane == 0) gadd(cntB);
                if (lane == 0) lset(&sflag[2], t + 1);
            }
        } else {  // wid == 3: LN/dt producer, runs ahead under back-pressure
            if (t < T_) {
                lwait(&sflag[0], t - 1);   // xn[p] & dt slot consumed by w0
                lwait(&sflag[2], t - 2);   // dt slot consumed by w2
                if (lane < 16) {
                    int m = lane;
                    const float* xp = xs + ((size_t)(b0+m) * T_ + t) * S_;
                    float v[8]; float mu = 0.f;
                    #pragma unroll
                    for (int s = 0; s < 8; ++s) { v[s] = xp[s]; mu += v[s]; }
                    mu *= 0.125f;
                    float var = 0.f;
                    #pragma unroll
                    for (int s = 0; s < 8; ++s) { float d = v[s] - mu; var += d * d; }
                    var *= 0.125f;
                    float rstd = rsqrtf(var + 1e-5f);
                    #pragma unroll
                    for (int s = 0; s < 8; ++s)
                        s_xn[p][m][s] = (v[s] - mu) * rstd * lngv[s] + lnbv[s];
                    float ts = tstamp[(size_t)(b0+m) * T_ + t];
                    float dt = (t == 0) ? 1.0f : fmaxf(ts - tsPrev, 1e-6f);
                    tsPrev = ts;
                    s_dt[t & 3][m] = dt;
                }
                if (lane == 0) lset(&sflag[3], t + 1);
            }
        }
    }

    // ---- latent head (wave0): final h1 = step T-1, fp32 in h1fin ----
    if (wid == 0) {
        gpoll(cntB, 16 * T_);   // all wave2 pubs incl. h1fin drained
        if (lane < 32) {
            int lb = lane >> 1;
            int l  = j*2 + (lane & 1);
            const float* hsrc = h1fin + (size_t)(b0+lb) * H_;
            float acc = lp_b[l];
            #pragma unroll 8
            for (int k = 0; k < H_; ++k)
                acc += __hip_atomic_load(&hsrc[k], __ATOMIC_RELAXED, __HIP_MEMORY_SCOPE_AGENT)
                       * lp_w[l*H_ + k];
            float lat = tanhf(acc);
            out[(b0+lb)*L_ + l] = lat;
            __hip_atomic_store(&latg[(b0+lb)*L_ + l], lat,
                               __ATOMIC_RELAXED, __HIP_MEMORY_SCOPE_AGENT);
        }
        vwait0();
        if (lane == 0) gadd(cntC);

        // ---- risk head (block j==0 of each cluster) ----
        if (j == 0) {
            gpoll(cntC, 16);
            if (lane < 16) {
                float latv[L_];
                #pragma unroll
                for (int l = 0; l < L_; ++l)
                    latv[l] = __hip_atomic_load(&latg[(b0+lane)*L_ + l],
                                                __ATOMIC_RELAXED, __HIP_MEMORY_SCOPE_AGENT);
                float acc2 = r2_b[0];
                for (int j2 = 0; j2 < RH_; ++j2) {
                    float z = r1_b[j2];
                    #pragma unroll
                    for (int l = 0; l < L_; ++l) z += r1_w[j2*L_ + l] * latv[l];
                    float hid = 0.5f * z * (1.f + erff(z * 0.70710678118654752f));
                    acc2 += r2_w[j2] * hid;
                }
                out[B_*L_ + b0 + lane] = 1.f / (1.f + expf(-acc2));
            }
        }
    }
}

extern "C" void kernel_launch(void* const* d_in, const int* in_sizes, int n_in,
                              void* d_out, int out_size, void* d_ws, size_t ws_size,
                              hipStream_t stream) {
    (void)in_sizes; (void)n_in; (void)out_size; (void)ws_size;
    const float* xs     = (const float*)d_in[0];
    const float* tstamp = (const float*)d_in[1];
    const float* ln_g   = (const float*)d_in[2];
    const float* ln_b   = (const float*)d_in[3];
    const float* bb_w0  = (const float*)d_in[4];
    const float* bb_b0  = (const float*)d_in[5];
    const float* gx_w0  = (const float*)d_in[6];
    const float* gx_b0  = (const float*)d_in[7];
    const float* gh_w0  = (const float*)d_in[8];
    const float* gb0    = (const float*)d_in[9];
    const float* lt0    = (const float*)d_in[10];
    const float* bb_w1  = (const float*)d_in[11];
    const float* bb_b1  = (const float*)d_in[12];
    const float* gx_w1  = (const float*)d_in[13];
    const float* gx_b1  = (const float*)d_in[14];
    const float* gh_w1  = (const float*)d_in[15];
    const float* gb1    = (const float*)d_in[16];
    const float* lt1    = (const float*)d_in[17];
    const float* lp_w   = (const float*)d_in[18];
    const float* lp_b   = (const float*)d_in[19];
    const float* r1_w   = (const float*)d_in[20];
    const float* r1_b   = (const float*)d_in[21];
    const float* r2_w   = (const float*)d_in[22];
    const float* r2_b   = (const float*)d_in[23];

    // ws carve: bar 4KB | h0pub 2*FH | h1pub 2*FH | h1fin FH | latg B*L
    uint8_t* w = (uint8_t*)d_ws;
    int*   bar   = (int*)w;
    float* h0pub = (float*)(w + 4096);
    float* h1pub = h0pub + 2 * FH;
    float* h1fin = h1pub + 2 * FH;
    float* latg  = h1fin + FH;

    hipMemsetAsync(d_ws, 0,
                   4096 + (size_t)(5 * FH + B_ * L_) * sizeof(float), stream);

    liquid_cfc_mfma<<<dim3(NC * CB), dim3(TPB), 0, stream>>>(
        xs, tstamp, ln_g, ln_b,
        bb_w0, bb_b0, gx_w0, gx_b0, gh_w0, gb0, lt0,
        bb_w1, bb_b1, gx_w1, gx_b1, gh_w1, gb1, lt1,
        lp_w, lp_b, r1_w, r1_b, r2_w, r2_b,
        (float*)d_out, bar, h0pub, h1pub, h1fin, latg);
}

// Round 10
// 5190.867 us; speedup vs baseline: 1.1435x; 1.1435x over previous
//
#include <hip/hip_runtime.h>
#include <math.h>

#define B_  256
#define T_  1024
#define S_  8
#define H_  256
#define L_  32
#define RH_ 32
#define NC  16   // clusters (batch groups of 16)
#define CB  16   // blocks per cluster (16 H-rows each)
#define MB  16   // batch rows per cluster
#define NR  16   // H rows per block
#define TPB 256  // 4 waves: w0=layer0(t), w1=layer1 x-side(t-1), w2=layer1(t-2), w3=LN/dt(t+1)
#define FH  (B_*H_)   // 65536 floats per parity plane
#define CS  (MB*H_)   // 4096 floats: one cluster's slice of a plane

typedef __attribute__((ext_vector_type(8))) short bf16x8;   // 8 bf16 = 4 VGPRs
typedef __attribute__((ext_vector_type(4))) float f32x4;
typedef unsigned long long ull;

__device__ __forceinline__ void split_bf16(float v, short& hi, short& lo) {
    unsigned ub = __float_as_uint(v);
    float hf = __uint_as_float(ub & 0xffff0000u);   // truncate to bf16 (exact residual below)
    hi = (short)(ub >> 16);
    lo = (short)(__float_as_uint(v - hf) >> 16);    // residual truncated to bf16: ~2^-16 rel total
}

// Fragment-order exchange (r8-proven): per kb, wave reads base + lane*32B,
// fully contiguous 2KB, 1 request/line, zero redundancy. Unpack identical
// to r8 -> bit-identical results.
__device__ __forceinline__ void exch_mfma(
    const float* src, int lane,
    const bf16x8 (&whi)[2][8], const bf16x8 (&wlo)[2][8],
    f32x4& accg, f32x4& accf)
{
    const ull* hsrc = (const ull*)src;
    ull araw[32];
    #pragma unroll
    for (int u = 0; u < 32; ++u) {
        int kb = u >> 2, uu = u & 3;
        araw[u] = __hip_atomic_load(&hsrc[kb*256 + lane*4 + uu],
                                    __ATOMIC_RELAXED, __HIP_MEMORY_SCOPE_AGENT);
    }
    #pragma unroll
    for (int kb = 0; kb < 8; ++kb) {
        bf16x8 ahi, alo;
        #pragma unroll
        for (int uu = 0; uu < 4; ++uu) {
            ull d = araw[kb*4 + uu];
            float f0 = __uint_as_float((unsigned)d);
            float f1 = __uint_as_float((unsigned)(d >> 32));
            short h_, l_;
            split_bf16(f0, h_, l_); ahi[uu*2]   = h_; alo[uu*2]   = l_;
            split_bf16(f1, h_, l_); ahi[uu*2+1] = h_; alo[uu*2+1] = l_;
        }
        accg = __builtin_amdgcn_mfma_f32_16x16x32_bf16(ahi, whi[0][kb], accg, 0,0,0);
        accg = __builtin_amdgcn_mfma_f32_16x16x32_bf16(alo, whi[0][kb], accg, 0,0,0);
        accg = __builtin_amdgcn_mfma_f32_16x16x32_bf16(ahi, wlo[0][kb], accg, 0,0,0);
        accf = __builtin_amdgcn_mfma_f32_16x16x32_bf16(ahi, whi[1][kb], accf, 0,0,0);
        accf = __builtin_amdgcn_mfma_f32_16x16x32_bf16(alo, whi[1][kb], accf, 0,0,0);
        accf = __builtin_amdgcn_mfma_f32_16x16x32_bf16(ahi, wlo[1][kb], accf, 0,0,0);
    }
}

__global__ void __launch_bounds__(TPB, 1)
liquid_cfc_mfma(const float* __restrict__ xs,      // [B,T,S]
                const float* __restrict__ tstamp,  // [B,T]
                const float* __restrict__ ln_g, const float* __restrict__ ln_b,
                const float* __restrict__ bb_w0, const float* __restrict__ bb_b0,
                const float* __restrict__ gx_w0, const float* __restrict__ gx_b0,
                const float* __restrict__ gh_w0, const float* __restrict__ gb0,
                const float* __restrict__ lt0,
                const float* __restrict__ bb_w1, const float* __restrict__ bb_b1,
                const float* __restrict__ gx_w1, const float* __restrict__ gx_b1,
                const float* __restrict__ gh_w1, const float* __restrict__ gb1,
                const float* __restrict__ lt1,
                const float* __restrict__ lp_w, const float* __restrict__ lp_b,
                const float* __restrict__ r1_w, const float* __restrict__ r1_b,
                const float* __restrict__ r2_w, const float* __restrict__ r2_b,
                float* __restrict__ out,
                int*   bar,     // [NC*64] cluster counters, 256B apart (r0 structure)
                float* h0pub,   // [2][NC][CS] fp32, fragment-order exchange (r8)
                float* h1pub,   // [2][NC][CS]
                float* h1fin,   // [B][H] fp32 final h1, row-major (latent tail)
                float* latg)    // [B][L]
{
    const int tid  = threadIdx.x, lane = tid & 63, wid = tid >> 6;
    const int blk  = blockIdx.x,  c = blk >> 4,    j  = blk & 15;
    const int b0   = c * MB,      r0 = j * NR;
    const int n    = lane & 15,   quad = lane >> 4;
    int* cnt = &bar[c * 64];

    // Producer-side fragment-layout constants for k = r0 + n (r8-identical)
    const int kbp = j >> 1;
    const int qkp = ((j & 1) << 1) | (n >> 3);
    const int pbase = ((kbp*4 + qkp)*16)*8 + (n & 7);

    // Deep-pipeline LDS lifetimes (ONE barrier per epoch, all handoffs cross it):
    //  xn[2]  : step s in slot s&1, written by w3 at epoch s-1 (s=0: prologue);
    //           read by w0 at epoch s; slot rewritten at epoch s+1 (step s+2).
    //  dt[4]  : step s in slot s&3, written at epoch s-1; read by w0 at epoch s
    //           and w2 at epoch s+2; rewritten at epoch s+3.
    //  pg/pf[2]: partials for step s in slot (s+1)&1, written by w1 at epoch s+1;
    //           read by w2 at epoch s+2; rewritten at epoch s+3.
    __shared__ float s_xn[2][16][9];
    __shared__ float s_dt[4][16];
    __shared__ float s_gx0[16][9], s_bb0x[16][9];
    __shared__ float s_bg0[16], s_bf0[16], s_sp0[16];
    __shared__ float s_bg1[16], s_bf1[16], s_sp1[16];
    __shared__ float s_pg[2][16][17], s_pf[2][16][17];

    // ---- one-time LDS init ----
    if (tid < 16) {
        s_bg0[tid] = gx_b0[r0+tid] + gb0[r0+tid];
        s_bf0[tid] = bb_b0[r0+tid];
        s_sp0[tid] = log1pf(expf(lt0[r0+tid]));
        s_bg1[tid] = gx_b1[r0+tid] + gb1[r0+tid];
        s_bf1[tid] = bb_b1[r0+tid];
        s_sp1[tid] = log1pf(expf(lt1[r0+tid]));
    }
    if (tid < 128) {
        int r = tid >> 3, s = tid & 7;
        s_gx0[r][s]  = gx_w0[(r0+r)*S_ + s];
        s_bb0x[r][s] = bb_w0[(r0+r)*(S_+H_) + s];
    }

    // ---- one-time: weight slices -> bf16 hi/lo MFMA B-fragments (r8-identical) ----
    bf16x8 whi[2][8], wlo[2][8];
    if (wid < 3) {
        const float* base[2]; int st[2], of[2];
        if (wid == 0) { base[0]=gh_w0; st[0]=H_;   of[0]=0;  base[1]=bb_w0; st[1]=S_+H_; of[1]=S_; }
        else if (wid == 1) { base[0]=gx_w1; st[0]=H_; of[0]=0; base[1]=bb_w1; st[1]=2*H_; of[1]=0; }
        else { base[0]=gh_w1; st[0]=H_; of[0]=0; base[1]=bb_w1; st[1]=2*H_; of[1]=H_; }
        int row = r0 + n;
        for (int mt = 0; mt < 2; ++mt) {
            const float* bp = base[mt] + (size_t)row * st[mt] + of[mt];
            for (int kb = 0; kb < 8; ++kb) {
                const float* sp = bp + kb*32 + quad*8;
                #pragma unroll
                for (int jj = 0; jj < 8; ++jj) {
                    short h_, l_;
                    split_bf16(sp[jj], h_, l_);
                    whi[mt][kb][jj] = h_; wlo[mt][kb][jj] = l_;
                }
            }
        }
    }
    float lngv[8], lnbv[8];
    float tsPrev = 0.f;
    if (wid == 3 && lane < 16) {
        #pragma unroll
        for (int s = 0; s < 8; ++s) { lngv[s] = ln_g[s]; lnbv[s] = ln_b[s]; }
        // ---- prologue: LN(x_0), dt(0) -> slots 0 (covered by init barrier) ----
        int m = lane;
        const float* xp = xs + ((size_t)(b0+m) * T_) * S_;
        float v[8]; float mu = 0.f;
        #pragma unroll
        for (int s = 0; s < 8; ++s) { v[s] = xp[s]; mu += v[s]; }
        mu *= 0.125f;
        float var = 0.f;
        #pragma unroll
        for (int s = 0; s < 8; ++s) { float d = v[s] - mu; var += d * d; }
        var *= 0.125f;
        float rstd = rsqrtf(var + 1e-5f);
        #pragma unroll
        for (int s = 0; s < 8; ++s) s_xn[0][m][s] = (v[s] - mu) * rstd * lngv[s] + lnbv[s];
        s_dt[0][m] = 1.0f;
        tsPrev = tstamp[(size_t)(b0+m) * T_];
    }
    float h0own[4] = {0.f,0.f,0.f,0.f};   // wave0: own slice of h0 (fp32 exact)
    float h1own[4] = {0.f,0.f,0.f,0.f};   // wave2: own slice of h1
    __syncthreads();

    // ---- main loop: epoch t = layer0(t) | layer1-x(t-1) | layer1(t-2) | LN(t+1) ----
    // No intra-epoch cross-wave dependency: every handoff crosses the single
    // end-of-epoch barrier. All 4 waves issue LLC loads at barrier release.
    for (int t = 0; t <= T_ + 1; ++t) {
        const int p = t & 1, q = 1 - p;

        if (wid == 0) {
            if (t < T_) {
                f32x4 accg = {0.f,0.f,0.f,0.f}, accf = {0.f,0.f,0.f,0.f};
                exch_mfma(h0pub + (size_t)q*FH + (size_t)c*CS, lane, whi, wlo, accg, accf);
                #pragma unroll
                for (int i = 0; i < 4; ++i) {
                    int m = quad*4 + i;
                    float aG = accg[i] + s_bg0[n];
                    float aF = accf[i] + s_bf0[n];
                    #pragma unroll
                    for (int s = 0; s < 8; ++s) {
                        float xv = s_xn[p][m][s];     // step t, slot t&1 (epoch t-1)
                        aG += s_gx0[n][s] * xv;
                        aF += s_bb0x[n][s] * xv;
                    }
                    float g   = 1.f / (1.f + expf(-aG));
                    float f   = tanhf(aF);
                    float dec = expf(-s_dt[t & 3][m] * (s_sp0[n] + fabsf(g)));
                    h0own[i]  = dec * h0own[i] + (1.f - dec) * f;
                    __hip_atomic_store(&h0pub[(size_t)p*FH + (size_t)c*CS + pbase + m*8],
                                       h0own[i], __ATOMIC_RELAXED, __HIP_MEMORY_SCOPE_AGENT);
                }
            }
        } else if (wid == 1) {
            if (t >= 1 && t <= T_) {
                f32x4 accg = {0.f,0.f,0.f,0.f}, accf = {0.f,0.f,0.f,0.f};
                exch_mfma(h0pub + (size_t)q*FH + (size_t)c*CS, lane, whi, wlo, accg, accf);
                #pragma unroll
                for (int i = 0; i < 4; ++i) {        // partials for step t-1, slot t&1
                    s_pg[p][quad*4+i][n] = accg[i];
                    s_pf[p][quad*4+i][n] = accf[i];
                }
            }
        } else if (wid == 2) {
            if (t >= 2) {
                f32x4 accg = {0.f,0.f,0.f,0.f}, accf = {0.f,0.f,0.f,0.f};
                exch_mfma(h1pub + (size_t)q*FH + (size_t)c*CS, lane, whi, wlo, accg, accf);
                const int pgs = (t - 1) & 1;          // partials of step t-2 (epoch t-1)
                #pragma unroll
                for (int i = 0; i < 4; ++i) {
                    int m = quad*4 + i;
                    float aG = accg[i] + s_pg[pgs][m][n] + s_bg1[n];
                    float aF = accf[i] + s_pf[pgs][m][n] + s_bf1[n];
                    float g   = 1.f / (1.f + expf(-aG));
                    float f   = tanhf(aF);
                    float dec = expf(-s_dt[(t-2) & 3][m] * (s_sp1[n] + fabsf(g)));
                    h1own[i]  = dec * h1own[i] + (1.f - dec) * f;
                    __hip_atomic_store(&h1pub[(size_t)p*FH + (size_t)c*CS + pbase + m*8],
                                       h1own[i], __ATOMIC_RELAXED, __HIP_MEMORY_SCOPE_AGENT);
                    if (t == T_ + 1)   // final h1 = step T-1: bit-exact fp32 copy
                        __hip_atomic_store(&h1fin[(size_t)(b0+m)*H_ + (r0+n)], h1own[i],
                                           __ATOMIC_RELAXED, __HIP_MEMORY_SCOPE_AGENT);
                }
            }
        } else {  // wid == 3: LN/dt for step t+1 (step 0 done in prologue)
            if (t < T_ - 1 && lane < 16) {
                int m = lane, s1 = t + 1;
                const float* xp = xs + ((size_t)(b0+m) * T_ + s1) * S_;
                float v[8]; float mu = 0.f;
                #pragma unroll
                for (int s = 0; s < 8; ++s) { v[s] = xp[s]; mu += v[s]; }
                mu *= 0.125f;
                float var = 0.f;
                #pragma unroll
                for (int s = 0; s < 8; ++s) { float d = v[s] - mu; var += d * d; }
                var *= 0.125f;
                float rstd = rsqrtf(var + 1e-5f);
                #pragma unroll
                for (int s = 0; s < 8; ++s)
                    s_xn[s1 & 1][m][s] = (v[s] - mu) * rstd * lngv[s] + lnbv[s];
                float ts = tstamp[(size_t)(b0+m) * T_ + s1];
                s_dt[s1 & 3][m] = fmaxf(ts - tsPrev, 1e-6f);
                tsPrev = ts;
            }
        }

        // end-of-epoch cluster barrier (r0 structure, fastest measured):
        // syncthreads drains each wave's stores (vmcnt(0) before s_barrier);
        // tid0's add+poll closes the cluster; second syncthreads releases.
        __syncthreads();
        if (tid == 0) {
            __hip_atomic_fetch_add(cnt, 1, __ATOMIC_RELAXED, __HIP_MEMORY_SCOPE_AGENT);
            int tgt = (t + 1) * CB;
            while (__hip_atomic_load(cnt, __ATOMIC_RELAXED, __HIP_MEMORY_SCOPE_AGENT) < tgt) { }
        }
        __syncthreads();
    }

    // ---- latent head: final h1 (step T-1) in h1fin, fp32 exact ----
    if (tid < 32) {
        int lb = tid >> 1;
        int l  = j*2 + (tid & 1);
        const float* hsrc = h1fin + (size_t)(b0+lb) * H_;
        float acc = lp_b[l];
        #pragma unroll 8
        for (int k = 0; k < H_; ++k)
            acc += __hip_atomic_load(&hsrc[k], __ATOMIC_RELAXED, __HIP_MEMORY_SCOPE_AGENT)
                   * lp_w[l*H_ + k];
        float lat = tanhf(acc);
        out[(b0+lb)*L_ + l] = lat;
        __hip_atomic_store(&latg[(b0+lb)*L_ + l], lat,
                           __ATOMIC_RELAXED, __HIP_MEMORY_SCOPE_AGENT);
    }
    __syncthreads();
    if (tid == 0) {
        __hip_atomic_fetch_add(cnt, 1, __ATOMIC_RELAXED, __HIP_MEMORY_SCOPE_AGENT);
        int tgt = (T_ + 3) * CB;
        while (__hip_atomic_load(cnt, __ATOMIC_RELAXED, __HIP_MEMORY_SCOPE_AGENT) < tgt) { }
    }
    __syncthreads();

    // ---- risk head (block 0 of each cluster) ----
    if (j == 0 && tid < 16) {
        float latv[L_];
        #pragma unroll
        for (int l = 0; l < L_; ++l)
            latv[l] = __hip_atomic_load(&latg[(b0+tid)*L_ + l],
                                        __ATOMIC_RELAXED, __HIP_MEMORY_SCOPE_AGENT);
        float acc2 = r2_b[0];
        for (int j2 = 0; j2 < RH_; ++j2) {
            float z = r1_b[j2];
            #pragma unroll
            for (int l = 0; l < L_; ++l) z += r1_w[j2*L_ + l] * latv[l];
            float hid = 0.5f * z * (1.f + erff(z * 0.70710678118654752f)); // exact GELU
            acc2 += r2_w[j2] * hid;
        }
        out[B_*L_ + b0 + tid] = 1.f / (1.f + expf(-acc2));
    }
}

extern "C" void kernel_launch(void* const* d_in, const int* in_sizes, int n_in,
                              void* d_out, int out_size, void* d_ws, size_t ws_size,
                              hipStream_t stream) {
    (void)in_sizes; (void)n_in; (void)out_size; (void)ws_size;
    const float* xs     = (const float*)d_in[0];
    const float* tstamp = (const float*)d_in[1];
    const float* ln_g   = (const float*)d_in[2];
    const float* ln_b   = (const float*)d_in[3];
    const float* bb_w0  = (const float*)d_in[4];
    const float* bb_b0  = (const float*)d_in[5];
    const float* gx_w0  = (const float*)d_in[6];
    const float* gx_b0  = (const float*)d_in[7];
    const float* gh_w0  = (const float*)d_in[8];
    const float* gb0    = (const float*)d_in[9];
    const float* lt0    = (const float*)d_in[10];
    const float* bb_w1  = (const float*)d_in[11];
    const float* bb_b1  = (const float*)d_in[12];
    const float* gx_w1  = (const float*)d_in[13];
    const float* gx_b1  = (const float*)d_in[14];
    const float* gh_w1  = (const float*)d_in[15];
    const float* gb1    = (const float*)d_in[16];
    const float* lt1    = (const float*)d_in[17];
    const float* lp_w   = (const float*)d_in[18];
    const float* lp_b   = (const float*)d_in[19];
    const float* r1_w   = (const float*)d_in[20];
    const float* r1_b   = (const float*)d_in[21];
    const float* r2_w   = (const float*)d_in[22];
    const float* r2_b   = (const float*)d_in[23];

    // ws carve: bar 4KB | h0pub 2*FH | h1pub 2*FH | h1fin FH | latg B*L
    uint8_t* w = (uint8_t*)d_ws;
    int*   bar   = (int*)w;
    float* h0pub = (float*)(w + 4096);
    float* h1pub = h0pub + 2 * FH;
    float* h1fin = h1pub + 2 * FH;
    float* latg  = h1fin + FH;

    hipMemsetAsync(d_ws, 0,
                   4096 + (size_t)(5 * FH + B_ * L_) * sizeof(float), stream);

    liquid_cfc_mfma<<<dim3(NC * CB), dim3(TPB), 0, stream>>>(
        xs, tstamp, ln_g, ln_b,
        bb_w0, bb_b0, gx_w0, gx_b0, gh_w0, gb0, lt0,
        bb_w1, bb_b1, gx_w1, gx_b1, gh_w1, gb1, lt1,
        lp_w, lp_b, r1_w, r1_b, r2_w, r2_b,
        (float*)d_out, bar, h0pub, h1pub, h1fin, latg);
}

// Round 11
// 3756.174 us; speedup vs baseline: 1.5803x; 1.3820x over previous
//
#include <hip/hip_runtime.h>
#include <math.h>

#define B_  256
#define T_  1024
#define S_  8
#define H_  256
#define L_  32
#define RH_ 32
#define NC  16   // clusters (batch groups of 16)
#define CB  16   // blocks per cluster (16 H-rows each)
#define MB  16   // batch rows per cluster
#define NR  16   // H rows per block
#define TPB 256  // 4 waves: w0=layer0 MFMA, w1=layer1 x-side MFMA, w2=layer1 h-side MFMA, w3=LN/dt
#define FH  (B_*H_)   // 65536 floats per parity plane
#define CS  (MB*H_)   // 4096 floats: one cluster's slice of a plane

typedef __attribute__((ext_vector_type(8))) short bf16x8;   // 8 bf16 = 4 VGPRs
typedef __attribute__((ext_vector_type(4))) float f32x4;
typedef unsigned long long ull;
typedef unsigned int uint32;

__device__ __forceinline__ void split_bf16(float v, short& hi, short& lo) {
    unsigned ub = __float_as_uint(v);
    float hf = __uint_as_float(ub & 0xffff0000u);   // truncate to bf16 (exact residual below)
    hi = (short)(ub >> 16);
    lo = (short)(__float_as_uint(v - hf) >> 16);    // residual truncated to bf16: ~2^-16 rel total
}

__device__ __forceinline__ void vwait0() { asm volatile("s_waitcnt vmcnt(0)" ::: "memory"); }

// sc0-only 8B load: bypass L1, served by this XCD's L2 (local mode only —
// cluster verified single-XCD). "=&v" EARLY-CLOBBER is essential: without it
// the result may alias the address pair (the r2/r3 hang). Caller must vwait0
// before consuming.
__device__ __forceinline__ ull ld64_sc0(const ull* p) {
    ull r;
    asm volatile("global_load_dwordx2 %0, %1, off sc0" : "=&v"(r) : "v"(p));
    return r;
}
__device__ __forceinline__ void st32_sc0(float* p, float v) {
    asm volatile("global_store_dword %0, %1, off sc0" : : "v"(p), "v"(v) : "memory");
}

// Fragment-order exchange (r8-proven layout): per kb, wave reads base+lane*32B,
// fully contiguous 2KB, 1 request/line. L=true: sc0 asm loads (XCD L2).
// L=false: agent-scope hip atomics (r8 path, bit-identical). Unpack identical.
template<bool L>
__device__ __forceinline__ void exch_mfma(
    const float* src, int lane,
    const bf16x8 (&whi)[2][8], const bf16x8 (&wlo)[2][8],
    f32x4& accg, f32x4& accf)
{
    const ull* hsrc = (const ull*)src;
    ull araw[32];
    #pragma unroll
    for (int u = 0; u < 32; ++u) {
        int kb = u >> 2, uu = u & 3;
        const ull* ap = &hsrc[kb*256 + lane*4 + uu];
        if constexpr (L) araw[u] = ld64_sc0(ap);
        else araw[u] = __hip_atomic_load(ap, __ATOMIC_RELAXED, __HIP_MEMORY_SCOPE_AGENT);
    }
    if constexpr (L) { vwait0(); __builtin_amdgcn_sched_barrier(0); }
    #pragma unroll
    for (int kb = 0; kb < 8; ++kb) {
        bf16x8 ahi, alo;
        #pragma unroll
        for (int uu = 0; uu < 4; ++uu) {
            ull d = araw[kb*4 + uu];
            float f0 = __uint_as_float((unsigned)d);
            float f1 = __uint_as_float((unsigned)(d >> 32));
            short h_, l_;
            split_bf16(f0, h_, l_); ahi[uu*2]   = h_; alo[uu*2]   = l_;
            split_bf16(f1, h_, l_); ahi[uu*2+1] = h_; alo[uu*2+1] = l_;
        }
        accg = __builtin_amdgcn_mfma_f32_16x16x32_bf16(ahi, whi[0][kb], accg, 0,0,0);
        accg = __builtin_amdgcn_mfma_f32_16x16x32_bf16(alo, whi[0][kb], accg, 0,0,0);
        accg = __builtin_amdgcn_mfma_f32_16x16x32_bf16(ahi, wlo[0][kb], accg, 0,0,0);
        accf = __builtin_amdgcn_mfma_f32_16x16x32_bf16(ahi, whi[1][kb], accf, 0,0,0);
        accf = __builtin_amdgcn_mfma_f32_16x16x32_bf16(alo, whi[1][kb], accf, 0,0,0);
        accf = __builtin_amdgcn_mfma_f32_16x16x32_bf16(ahi, wlo[1][kb], accf, 0,0,0);
    }
}

__device__ __forceinline__ void pub32(bool local, float* p, float v) {
    if (local) st32_sc0(p, v);
    else __hip_atomic_store(p, v, __ATOMIC_RELAXED, __HIP_MEMORY_SCOPE_AGENT);
}

__global__ void __launch_bounds__(TPB, 1)
liquid_cfc_mfma(const float* __restrict__ xs,      // [B,T,S]
                const float* __restrict__ tstamp,  // [B,T]
                const float* __restrict__ ln_g, const float* __restrict__ ln_b,
                const float* __restrict__ bb_w0, const float* __restrict__ bb_b0,
                const float* __restrict__ gx_w0, const float* __restrict__ gx_b0,
                const float* __restrict__ gh_w0, const float* __restrict__ gb0,
                const float* __restrict__ lt0,
                const float* __restrict__ bb_w1, const float* __restrict__ bb_b1,
                const float* __restrict__ gx_w1, const float* __restrict__ gx_b1,
                const float* __restrict__ gh_w1, const float* __restrict__ gb1,
                const float* __restrict__ lt1,
                const float* __restrict__ lp_w, const float* __restrict__ lp_b,
                const float* __restrict__ r1_w, const float* __restrict__ r1_b,
                const float* __restrict__ r2_w, const float* __restrict__ r2_b,
                float* __restrict__ out,
                int*   bar,     // [NC*64] cluster counters, 256B apart (r0/r8 structure)
                int*   votes,   // [NC*16] XCD votes
                float* h0pub,   // [2][NC][CS] fp32, fragment-order exchange (r8)
                float* h1pub,   // [2][NC][CS]
                float* h1fin,   // [B][H] fp32 final h1, row-major (latent tail)
                float* latg)    // [B][L]
{
    const int tid  = threadIdx.x, lane = tid & 63, wid = tid >> 6;
    // Bijective remap so that under round-robin block->XCD dispatch (b%8,
    // grid=256=#CUs, 1 block/CU => all co-resident) each cluster's 16 blocks
    // share one XCD. Pure relabeling: correct under ANY placement; the vote
    // below verifies actual placement before enabling sc0-local exchange.
    const int b = (int)blockIdx.x;
    const int x = b & 7, idx = b >> 3;
    const int c = (x << 1) | (idx >> 4), j = idx & 15;
    const int b0 = c * MB, r0 = j * NR;
    const int n    = lane & 15,   quad = lane >> 4;
    int* cnt = &bar[c * 64];

    int xcd;
    asm volatile("s_getreg_b32 %0, hwreg(HW_REG_XCC_ID)" : "=s"(xcd));
    xcd &= 7;

    // Producer-side fragment-layout constants for k = r0 + n (r8-identical)
    const int kbp = j >> 1;
    const int qkp = ((j & 1) << 1) | (n >> 3);
    const int pbase = ((kbp*4 + qkp)*16)*8 + (n & 7);

    __shared__ float s_xn[16][9];            // +1 pad
    __shared__ float s_dt[2][16];            // dt double-buffered by epoch parity
    __shared__ float s_gx0[16][9], s_bb0x[16][9];
    __shared__ float s_bg0[16], s_bf0[16], s_sp0[16];
    __shared__ float s_bg1[16], s_bf1[16], s_sp1[16];
    __shared__ float s_pg[16][17], s_pf[16][17];   // wave1 -> wave2 partials
    __shared__ int   s_vote[16];
    __shared__ int   s_mode;

    // ---- per-cluster XCD vote (proven hip atomics; waits only on the 16
    //      co-resident peers — same liveness class as the epoch barrier) ----
    if (tid == 0)
        __hip_atomic_store(&votes[c*16 + j], xcd + 1,
                           __ATOMIC_RELAXED, __HIP_MEMORY_SCOPE_AGENT);
    if (tid < 16) {
        int v;
        do { v = __hip_atomic_load(&votes[c*16 + tid],
                                   __ATOMIC_RELAXED, __HIP_MEMORY_SCOPE_AGENT); }
        while (v == 0);
        s_vote[tid] = v;
    }

    // ---- one-time LDS init ----
    if (tid < 16) {
        s_bg0[tid] = gx_b0[r0+tid] + gb0[r0+tid];
        s_bf0[tid] = bb_b0[r0+tid];
        s_sp0[tid] = log1pf(expf(lt0[r0+tid]));
        s_bg1[tid] = gx_b1[r0+tid] + gb1[r0+tid];
        s_bf1[tid] = bb_b1[r0+tid];
        s_sp1[tid] = log1pf(expf(lt1[r0+tid]));
    }
    if (tid < 128) {
        int r = tid >> 3, s = tid & 7;
        s_gx0[r][s]  = gx_w0[(r0+r)*S_ + s];
        s_bb0x[r][s] = bb_w0[(r0+r)*(S_+H_) + s];
    }

    // ---- one-time: weight slices -> bf16 hi/lo MFMA B-fragments (r8-identical) ----
    bf16x8 whi[2][8], wlo[2][8];
    if (wid < 3) {
        const float* base[2]; int st[2], of[2];
        if (wid == 0) { base[0]=gh_w0; st[0]=H_;   of[0]=0;  base[1]=bb_w0; st[1]=S_+H_; of[1]=S_; }
        else if (wid == 1) { base[0]=gx_w1; st[0]=H_; of[0]=0; base[1]=bb_w1; st[1]=2*H_; of[1]=0; }
        else { base[0]=gh_w1; st[0]=H_; of[0]=0; base[1]=bb_w1; st[1]=2*H_; of[1]=H_; }
        int row = r0 + n;
        for (int mt = 0; mt < 2; ++mt) {
            const float* bp = base[mt] + (size_t)row * st[mt] + of[mt];
            for (int kb = 0; kb < 8; ++kb) {
                const float* sp = bp + kb*32 + quad*8;
                #pragma unroll
                for (int jj = 0; jj < 8; ++jj) {
                    short h_, l_;
                    split_bf16(sp[jj], h_, l_);
                    whi[mt][kb][jj] = h_; wlo[mt][kb][jj] = l_;
                }
            }
        }
    }
    float lngv[8], lnbv[8];
    if (wid == 3 && lane < 16) {
        #pragma unroll
        for (int s = 0; s < 8; ++s) { lngv[s] = ln_g[s]; lnbv[s] = ln_b[s]; }
    }
    __syncthreads();   // s_vote ready
    if (tid == 0) {
        int ok = 1;
        #pragma unroll
        for (int i = 0; i < 16; ++i) ok &= (s_vote[i] == xcd + 1);
        s_mode = ok ? 1 : 2;
    }
    float h0own[4] = {0.f,0.f,0.f,0.f};   // wave0: own slice of h0 (fp32 exact)
    float h1own[4] = {0.f,0.f,0.f,0.f};   // wave2: own slice of h1
    float tsPrev = 0.f;
    __syncthreads();   // s_mode + LDS init ready
    const bool local = (s_mode == 1);

    // ---- main loop: epoch t computes layer0(step t) and layer1(step t-1) ----
    for (int t = 0; t <= T_; ++t) {
        const int p = t & 1, q = 1 - p;
        const bool act = (wid == 0 || wid == 3) ? (t < T_) : (t >= 1);

        // wave3: layernorm x_t + dt
        if (wid == 3 && act && lane < 16) {
            int m = lane;
            const float* xp = xs + ((size_t)(b0+m) * T_ + t) * S_;
            float v[8]; float mu = 0.f;
            #pragma unroll
            for (int s = 0; s < 8; ++s) { v[s] = xp[s]; mu += v[s]; }
            mu *= 0.125f;
            float var = 0.f;
            #pragma unroll
            for (int s = 0; s < 8; ++s) { float d = v[s] - mu; var += d * d; }
            var *= 0.125f;
            float rstd = rsqrtf(var + 1e-5f);
            #pragma unroll
            for (int s = 0; s < 8; ++s) s_xn[m][s] = (v[s] - mu) * rstd * lngv[s] + lnbv[s];
            float ts = tstamp[(size_t)(b0+m) * T_ + t];
            float dt = (t == 0) ? 1.0f : fmaxf(ts - tsPrev, 1e-6f);
            tsPrev = ts;
            s_dt[p][m] = dt;
        }

        // waves 0-2: coalesced fragment-order A loads, split, 3-term MFMA
        f32x4 accg = {0.f,0.f,0.f,0.f}, accf = {0.f,0.f,0.f,0.f};
        if (wid < 3 && act) {
            const float* plane = (wid == 2) ? h1pub : h0pub;
            const float* src = plane + (size_t)q*FH + (size_t)c*CS;
            if (local) exch_mfma<true >(src, lane, whi, wlo, accg, accf);
            else       exch_mfma<false>(src, lane, whi, wlo, accg, accf);
            if (wid == 1) {
                #pragma unroll
                for (int i = 0; i < 4; ++i) {
                    s_pg[quad*4+i][n] = accg[i];
                    s_pf[quad*4+i][n] = accf[i];
                }
            }
        }
        __syncthreads();   // sync#1: xn/dt ready; wave1 partials ready

        // wave0 epilogue: layer-0 cell for step t, publish h0[t] (fragment order)
        if (wid == 0 && act) {
            #pragma unroll
            for (int i = 0; i < 4; ++i) {
                int m = quad*4 + i;
                float aG = accg[i] + s_bg0[n];
                float aF = accf[i] + s_bf0[n];
                #pragma unroll
                for (int s = 0; s < 8; ++s) {
                    float xv = s_xn[m][s];
                    aG += s_gx0[n][s] * xv;
                    aF += s_bb0x[n][s] * xv;
                }
                float g   = 1.f / (1.f + expf(-aG));
                float f   = tanhf(aF);
                float dec = expf(-s_dt[p][m] * (s_sp0[n] + fabsf(g)));
                h0own[i]  = dec * h0own[i] + (1.f - dec) * f;
                pub32(local, &h0pub[(size_t)p*FH + (size_t)c*CS + pbase + m*8], h0own[i]);
            }
            vwait0();   // asm stores are untracked by the compiler -> explicit drain
        }
        // wave2 epilogue: layer-1 cell for step t-1, publish h1[t-1] (fragment order)
        if (wid == 2 && t >= 1) {
            #pragma unroll
            for (int i = 0; i < 4; ++i) {
                int m = quad*4 + i;
                float aG = accg[i] + s_pg[m][n] + s_bg1[n];
                float aF = accf[i] + s_pf[m][n] + s_bf1[n];
                float g   = 1.f / (1.f + expf(-aG));
                float f   = tanhf(aF);
                float dec = expf(-s_dt[q][m] * (s_sp1[n] + fabsf(g)));
                h1own[i]  = dec * h1own[i] + (1.f - dec) * f;
                pub32(local, &h1pub[(size_t)p*FH + (size_t)c*CS + pbase + m*8], h1own[i]);
                if (t == T_)   // bit-exact fp32 row-major copy for the tail (agent)
                    __hip_atomic_store(&h1fin[(size_t)(b0+m)*H_ + (r0+n)], h1own[i],
                                       __ATOMIC_RELAXED, __HIP_MEMORY_SCOPE_AGENT);
            }
            vwait0();
        }

        // cluster barrier (r0/r8 structure, fastest measured). In local mode the
        // agent-scope counter also provides the temporal fence: each block's
        // publishes are already drained into the shared XCD L2 (vwait0 above)
        // before its tid0 increments, so sc0 readers after release see them.
        __syncthreads();
        if (tid == 0) {
            __hip_atomic_fetch_add(cnt, 1, __ATOMIC_RELAXED, __HIP_MEMORY_SCOPE_AGENT);
            int tgt = (t + 1) * CB;
            while (__hip_atomic_load(cnt, __ATOMIC_RELAXED, __HIP_MEMORY_SCOPE_AGENT) < tgt) { }
        }
        __syncthreads();
    }

    // ---- latent head: final h1 (step T-1) in h1fin, fp32 exact (agent) ----
    if (tid < 32) {
        int lb = tid >> 1;
        int l  = j*2 + (tid & 1);
        const float* hsrc = h1fin + (size_t)(b0+lb) * H_;
        float acc = lp_b[l];
        #pragma unroll 8
        for (int k = 0; k < H_; ++k)
            acc += __hip_atomic_load(&hsrc[k], __ATOMIC_RELAXED, __HIP_MEMORY_SCOPE_AGENT)
                   * lp_w[l*H_ + k];
        float lat = tanhf(acc);
        out[(b0+lb)*L_ + l] = lat;
        __hip_atomic_store(&latg[(b0+lb)*L_ + l], lat,
                           __ATOMIC_RELAXED, __HIP_MEMORY_SCOPE_AGENT);
    }
    __syncthreads();
    if (tid == 0) {
        __hip_atomic_fetch_add(cnt, 1, __ATOMIC_RELAXED, __HIP_MEMORY_SCOPE_AGENT);
        int tgt = (T_ + 2) * CB;
        while (__hip_atomic_load(cnt, __ATOMIC_RELAXED, __HIP_MEMORY_SCOPE_AGENT) < tgt) { }
    }
    __syncthreads();

    // ---- risk head (block j==0 of each cluster) ----
    if (j == 0 && tid < 16) {
        float latv[L_];
        #pragma unroll
        for (int l = 0; l < L_; ++l)
            latv[l] = __hip_atomic_load(&latg[(b0+tid)*L_ + l],
                                        __ATOMIC_RELAXED, __HIP_MEMORY_SCOPE_AGENT);
        float acc2 = r2_b[0];
        for (int j2 = 0; j2 < RH_; ++j2) {
            float z = r1_b[j2];
            #pragma unroll
            for (int l = 0; l < L_; ++l) z += r1_w[j2*L_ + l] * latv[l];
            float hid = 0.5f * z * (1.f + erff(z * 0.70710678118654752f)); // exact GELU
            acc2 += r2_w[j2] * hid;
        }
        out[B_*L_ + b0 + tid] = 1.f / (1.f + expf(-acc2));
    }
}

extern "C" void kernel_launch(void* const* d_in, const int* in_sizes, int n_in,
                              void* d_out, int out_size, void* d_ws, size_t ws_size,
                              hipStream_t stream) {
    (void)in_sizes; (void)n_in; (void)out_size; (void)ws_size;
    const float* xs     = (const float*)d_in[0];
    const float* tstamp = (const float*)d_in[1];
    const float* ln_g   = (const float*)d_in[2];
    const float* ln_b   = (const float*)d_in[3];
    const float* bb_w0  = (const float*)d_in[4];
    const float* bb_b0  = (const float*)d_in[5];
    const float* gx_w0  = (const float*)d_in[6];
    const float* gx_b0  = (const float*)d_in[7];
    const float* gh_w0  = (const float*)d_in[8];
    const float* gb0    = (const float*)d_in[9];
    const float* lt0    = (const float*)d_in[10];
    const float* bb_w1  = (const float*)d_in[11];
    const float* bb_b1  = (const float*)d_in[12];
    const float* gx_w1  = (const float*)d_in[13];
    const float* gx_b1  = (const float*)d_in[14];
    const float* gh_w1  = (const float*)d_in[15];
    const float* gb1    = (const float*)d_in[16];
    const float* lt1    = (const float*)d_in[17];
    const float* lp_w   = (const float*)d_in[18];
    const float* lp_b   = (const float*)d_in[19];
    const float* r1_w   = (const float*)d_in[20];
    const float* r1_b   = (const float*)d_in[21];
    const float* r2_w   = (const float*)d_in[22];
    const float* r2_b   = (const float*)d_in[23];

    // ws carve: bar 4KB | votes 4KB | h0pub 2*FH | h1pub 2*FH | h1fin FH | latg B*L
    uint8_t* w = (uint8_t*)d_ws;
    int*   bar   = (int*)w;
    int*   votes = (int*)(w + 4096);
    float* h0pub = (float*)(w + 8192);
    float* h1pub = h0pub + 2 * FH;
    float* h1fin = h1pub + 2 * FH;
    float* latg  = h1fin + FH;

    hipMemsetAsync(d_ws, 0,
                   8192 + (size_t)(5 * FH + B_ * L_) * sizeof(float), stream);

    liquid_cfc_mfma<<<dim3(NC * CB), dim3(TPB), 0, stream>>>(
        xs, tstamp, ln_g, ln_b,
        bb_w0, bb_b0, gx_w0, gx_b0, gh_w0, gb0, lt0,
        bb_w1, bb_b1, gx_w1, gx_b1, gh_w1, gb1, lt1,
        lp_w, lp_b, r1_w, r1_b, r2_w, r2_b,
        (float*)d_out, bar, votes, h0pub, h1pub, h1fin, latg);
}